// Round 1
// baseline (209.451 us; speedup 1.0000x reference)
//
#include <hip/hip_runtime.h>
#include <hip/hip_bf16.h>

#define B_DIM 8
#define C_DIM 256
#define S_DIM 2304

// Padded LDS row stride for the 128x32 staging tiles: 40 bf16 = 80 B.
// 80 B = 20 banks -> frag ds_read_b128 start banks (fm*20 + 4g) mod 32 cover
// all 32 banks with exactly 2 lanes per 4-bank group (free, m136), vs the old
// 64 B stride which was an 8-way conflict (~2.9x on the binding LDS pipe).
// 16-B alignment preserved (80 % 16 == 0). 128 rows * 40 = 5120 elems/tile.
#define ROW_STRIDE 40
#define TILE_ELEMS (128 * ROW_STRIDE)

typedef __attribute__((ext_vector_type(8))) short short8;
typedef __attribute__((ext_vector_type(4))) float floatx4;

// Barrier that drains ONLY LDS ops (lgkmcnt), leaving register-destined
// global loads in flight across the barrier. __syncthreads() would force
// s_waitcnt vmcnt(0) and kill the prefetch overlap.
__device__ __forceinline__ void barrier_lgkm() {
    asm volatile("s_waitcnt lgkmcnt(0)\n\ts_barrier" ::: "memory");
}

// ---------------------------------------------------------------------------
// Kernel 1: per-(b,s) L2-normalize over C and transpose [B,C,S] f32 ->
// [B,S,C] bf16.  (unchanged; verified; ~traffic floor 9 us)
// ---------------------------------------------------------------------------
__global__ __launch_bounds__(256) void norm_transpose_kernel(
    const float* __restrict__ src, const float* __restrict__ dst,
    __hip_bfloat16* __restrict__ srcT, __hip_bfloat16* __restrict__ dstT) {
    const int s0 = blockIdx.x * 64;
    const int b  = blockIdx.y;
    const float* in = (blockIdx.z == 0 ? src : dst) + (size_t)b * C_DIM * S_DIM;
    __hip_bfloat16* out = (blockIdx.z == 0 ? srcT : dstT) + (size_t)b * S_DIM * C_DIM;

    __shared__ __align__(16) __hip_bfloat16 tile[64][C_DIM + 8];
    __shared__ float red[4][64];
    __shared__ float invn[64];

    const int t  = threadIdx.x;
    const int l  = t & 63;
    const int wv = t >> 6;

    float ss = 0.f;
#pragma unroll 8
    for (int c = wv; c < C_DIM; c += 4) {
        float v = in[(size_t)c * S_DIM + s0 + l];
        ss += v * v;
        tile[l][c] = __float2bfloat16(v);
    }
    red[wv][l] = ss;
    __syncthreads();
    if (t < 64) invn[t] = rsqrtf(red[0][t] + red[1][t] + red[2][t] + red[3][t]);
    __syncthreads();

#pragma unroll
    for (int it = 0; it < 8; ++it) {
        int idx  = it * 256 + t;
        int srow = idx >> 5;
        int c0   = (idx & 31) << 3;
        float inv = invn[srow];
        union { short8 v; __hip_bfloat16 h[8]; } u, o;
        u.v = *(const short8*)&tile[srow][c0];
#pragma unroll
        for (int j = 0; j < 8; ++j)
            o.h[j] = __float2bfloat16(__bfloat162float(u.h[j]) * inv);
        *(short8*)&out[(size_t)(s0 + srow) * C_DIM + c0] = o.v;
    }
}

// ---------------------------------------------------------------------------
// Kernel 2: per-batch GEMM  out[b][m][n] = relu( sum_k At[b][m][k]*Bt[b][n][k] )
// cp.async-style pipeline in HIP:
//   prologue: global_load tile 0 -> VGPRs
//   iter ki : ds_write regs -> buf[ki&1]   (vmcnt wait covers loads from ki-1,
//                                           hidden behind a full iteration)
//             global_load tile ki+1 -> regs (stays in flight ACROSS barrier)
//             s_waitcnt lgkmcnt(0); s_barrier   (no vmcnt drain!)
//             ds_read frags; 16x mfma_16x16x32_bf16  (setprio'd, T5)
// WAR safety: buf[ki&1] was last read in iter ki-2, two barriers earlier.
// Batch->XCD swizzle (batch = blockIdx.x % 8) keeps each batch's A+B
// (2.36 MB) resident in one XCD's 4 MB L2.
// This round: LDS rows padded 32->40 elems (conflict-free frag reads),
// s_setprio around the MFMA cluster.
// ---------------------------------------------------------------------------
__global__ __launch_bounds__(256) void gemm_relu_kernel(
    const __hip_bfloat16* __restrict__ At, const __hip_bfloat16* __restrict__ Bt,
    float* __restrict__ out) {
    const int id = blockIdx.x;
    const int b  = id & 7;          // batch -> XCD (id%8 round-robin)
    const int q  = id >> 3;
    const int m0 = (q % 18) * 128;
    const int n0 = (q / 18) * 128;
    const __hip_bfloat16* A  = At + (size_t)b * S_DIM * C_DIM;
    const __hip_bfloat16* Bp = Bt + (size_t)b * S_DIM * C_DIM;

    // LDS: As[p] at elems [p*5120), Bs[p] at [10240 + p*5120)  (40960 B total)
    // epilogue f32 Cs[64][132] (33792 B) aliased on top.
    // 40960 B/block -> still exactly 4 blocks/CU (160 KiB).
    __shared__ __align__(16) unsigned char smem[2 * 2 * TILE_ELEMS * 2];
    __hip_bfloat16* stg = (__hip_bfloat16*)smem;
    float* Cs = (float*)smem;

    const int t    = threadIdx.x;
    const int lane = t & 63;
    const int wv   = t >> 6;

    const int fm = lane & 15;
    const int kq = (lane >> 4) << 3;
    const int wr = (wv >> 1) << 6;
    const int wc = (wv & 1) << 6;
    const int rq = (lane >> 4) << 2;

    // Staging: logical tile = 128 rows x 32 k; wave wv owns elems
    // [wv*1024, wv*1024+512) via e0 and [+512, +1024) via e1.
    const int e0   = wv * 1024 + lane * 8;
    const int row0 = e0 >> 5, kc0 = e0 & 31;
    const int e1   = e0 + 512;
    const int row1 = e1 >> 5, kc1 = e1 & 31;
    // padded LDS element offsets
    const int p0 = row0 * ROW_STRIDE + kc0;
    const int p1 = row1 * ROW_STRIDE + kc1;

    const __hip_bfloat16* gA0 = A  + (size_t)(m0 + row0) * C_DIM + kc0;
    const __hip_bfloat16* gA1 = A  + (size_t)(m0 + row1) * C_DIM + kc1;
    const __hip_bfloat16* gB0 = Bp + (size_t)(n0 + row0) * C_DIM + kc0;
    const __hip_bfloat16* gB1 = Bp + (size_t)(n0 + row1) * C_DIM + kc1;

    // prologue: tile 0 -> registers
    short8 rA0 = *(const short8*)gA0;
    short8 rA1 = *(const short8*)gA1;
    short8 rB0 = *(const short8*)gB0;
    short8 rB1 = *(const short8*)gB1;

    floatx4 acc[4][4] = {};

#pragma unroll
    for (int ki = 0; ki < 8; ++ki) {
        __hip_bfloat16* As = stg + (ki & 1) * TILE_ELEMS;
        __hip_bfloat16* Bs = stg + 2 * TILE_ELEMS + (ki & 1) * TILE_ELEMS;

        // stage tile ki from regs into LDS (compiler inserts the vmcnt wait
        // for the loads issued one full iteration ago)
        *(short8*)(As + p0) = rA0;
        *(short8*)(As + p1) = rA1;
        *(short8*)(Bs + p0) = rB0;
        *(short8*)(Bs + p1) = rB1;

        // prefetch tile ki+1 -> regs; stays in flight across the barrier
        if (ki < 7) {
            int off = (ki + 1) * 32;
            rA0 = *(const short8*)(gA0 + off);
            rA1 = *(const short8*)(gA1 + off);
            rB0 = *(const short8*)(gB0 + off);
            rB1 = *(const short8*)(gB1 + off);
        }

        barrier_lgkm();   // drain LDS writes only; NO vmcnt drain

        short8 af[4], bf[4];
#pragma unroll
        for (int i = 0; i < 4; ++i) {
            af[i] = *(const short8*)&As[(wr + i * 16 + fm) * ROW_STRIDE + kq];
            bf[i] = *(const short8*)&Bs[(wc + i * 16 + fm) * ROW_STRIDE + kq];
        }
        __builtin_amdgcn_s_setprio(1);
#pragma unroll
        for (int i = 0; i < 4; ++i)
#pragma unroll
            for (int j = 0; j < 4; ++j)
                acc[i][j] = __builtin_amdgcn_mfma_f32_16x16x32_bf16(af[i], bf[j], acc[i][j], 0, 0, 0);
        __builtin_amdgcn_s_setprio(0);
    }

    // Epilogue: acc -> padded LDS f32 tile -> coalesced float4 stores, ReLU fused.
    float* Cp = out + (size_t)b * S_DIM * S_DIM;
#pragma unroll
    for (int p = 0; p < 2; ++p) {
        __syncthreads();   // all frag ds_reads / prior Cs reads done
#pragma unroll
        for (int i2 = 0; i2 < 2; ++i2) {
            int i = 2 * p + i2;
            int slot = (wr >> 1) + i2 * 16 + rq;
#pragma unroll
            for (int j = 0; j < 4; ++j) {
                int col = wc + j * 16 + fm;
#pragma unroll
                for (int r = 0; r < 4; ++r)
                    Cs[(slot + r) * 132 + col] = fmaxf(acc[i][j][r], 0.f);
            }
        }
        __syncthreads();
#pragma unroll
        for (int it = 0; it < 8; ++it) {
            int idx  = it * 256 + t;
            int srow = idx >> 5;
            int c4   = (idx & 31) << 2;
            float4 v = *(const float4*)&Cs[srow * 132 + c4];
            int lrow = 32 * p + (srow & 31) + ((srow >> 5) << 6);
            *(float4*)&Cp[(size_t)(m0 + lrow) * S_DIM + n0 + c4] = v;
        }
    }
}

extern "C" void kernel_launch(void* const* d_in, const int* in_sizes, int n_in,
                              void* d_out, int out_size, void* d_ws, size_t ws_size,
                              hipStream_t stream) {
    const float* src = (const float*)d_in[0];
    const float* dst = (const float*)d_in[1];
    float* out = (float*)d_out;

    __hip_bfloat16* srcT = (__hip_bfloat16*)d_ws;
    __hip_bfloat16* dstT = srcT + (size_t)B_DIM * S_DIM * C_DIM;

    dim3 g1(S_DIM / 64, B_DIM, 2);
    norm_transpose_kernel<<<g1, 256, 0, stream>>>(src, dst, srcT, dstT);

    gemm_relu_kernel<<<dim3(B_DIM * 18 * 18), 256, 0, stream>>>(srcT, dstT, out);
}